// Round 1
// baseline (21.235 us; speedup 1.0000x reference)
//
#include <hip/hip_runtime.h>
#include <math.h>

#define BLOCK 256
#define PPT 4                 // points per thread
#define MCOR 128
constexpr int Bb = 64;
constexpr int Nn = 16384;
constexpr int CCH = 6;

// main kernel: one block = one (batch, 1024-point slice)
__global__ __launch_bounds__(BLOCK) void acl_main(
    const float* __restrict__ inputs,
    const float* __restrict__ targets,
    const float* __restrict__ pts,      // [B,N,6]
    const float* __restrict__ corners,  // [B,M,3]
    float2* __restrict__ partials)
{
    __shared__ float4 cs[MCOR];
    __shared__ float2 wsum[BLOCK / 64];

    const int b   = blockIdx.y;
    const int tid = threadIdx.x;

    // stage corners: {-2cx, -2cy, -2cz, csq or +inf}
    if (tid < MCOR) {
        const float* c = corners + ((size_t)b * MCOR + tid) * 3;
        float cx = c[0], cy = c[1], cz = c[2];
        float csq = (cx > -1.0f) ? (cx*cx + cy*cy + cz*cz) : __builtin_inff();
        cs[tid] = make_float4(-2.0f*cx, -2.0f*cy, -2.0f*cz, csq);
    }
    __syncthreads();

    const int n0 = blockIdx.x * (BLOCK * PPT) + tid * PPT;
    const size_t base = (size_t)b * Nn + n0;

    const float4 x4 = *(const float4*)(inputs  + base);
    const float4 t4 = *(const float4*)(targets + base);
    const float4* pv = (const float4*)(pts + base * CCH);
    float4 v0 = pv[0], v1 = pv[1], v2 = pv[2], v3 = pv[3], v4 = pv[4], v5 = pv[5];

    float px[PPT] = {v0.x, v1.z, v3.x, v4.z};
    float py[PPT] = {v0.y, v1.w, v3.y, v4.w};
    float pz[PPT] = {v0.z, v2.x, v3.z, v5.x};

    float dmin[PPT] = {__builtin_inff(), __builtin_inff(), __builtin_inff(), __builtin_inff()};

    #pragma unroll 8
    for (int m = 0; m < MCOR; m += 2) {
        float4 c0 = cs[m];
        float4 c1 = cs[m + 1];
        #pragma unroll
        for (int j = 0; j < PPT; ++j) {
            float t0 = fmaf(c0.x, px[j], fmaf(c0.y, py[j], fmaf(c0.z, pz[j], c0.w)));
            float t1 = fmaf(c1.x, px[j], fmaf(c1.y, py[j], fmaf(c1.z, pz[j], c1.w)));
            dmin[j] = fminf(dmin[j], fminf(t0, t1));  // hopes for v_min3_f32
        }
    }

    const float xs[PPT] = {x4.x, x4.y, x4.z, x4.w};
    const float ts[PPT] = {t4.x, t4.y, t4.z, t4.w};
    float fs = 0.0f, ds = 0.0f;
    #pragma unroll
    for (int j = 0; j < PPT; ++j) {
        float psq = fmaf(px[j], px[j], fmaf(py[j], py[j], pz[j]*pz[j]));
        float d2  = fmaxf(psq + dmin[j], 1e-12f);
        float md  = sqrtf(d2);
        float w   = fmaf(2.0f, __expf(-10.0f * md), 1.0f);   // 1 + 2*exp(-md/0.1)

        float x = xs[j], t = ts[j];
        float ax = fabsf(x);
        float ce = fmaxf(x, 0.0f) - x*t + __logf(1.0f + __expf(-ax));
        float p  = 1.0f / (1.0f + __expf(-x));
        float pt = p*t + (1.0f - p)*(1.0f - t);
        float om = 1.0f - pt;
        float fe = om * om * ce;                              // ALPHA=1, GAMMA=2

        fs += fe;
        ds = fmaf(fe, w, ds);
    }

    // wave64 reduce
    #pragma unroll
    for (int off = 32; off > 0; off >>= 1) {
        fs += __shfl_down(fs, off, 64);
        ds += __shfl_down(ds, off, 64);
    }
    const int wave = tid >> 6, lane = tid & 63;
    if (lane == 0) wsum[wave] = make_float2(fs, ds);
    __syncthreads();
    if (tid == 0) {
        float F = 0.0f, D = 0.0f;
        #pragma unroll
        for (int w = 0; w < BLOCK / 64; ++w) { F += wsum[w].x; D += wsum[w].y; }
        partials[(size_t)blockIdx.y * gridDim.x + blockIdx.x] = make_float2(F, D);
    }
}

__global__ __launch_bounds__(256) void acl_final(
    const float2* __restrict__ partials, int n, float* __restrict__ out)
{
    double f = 0.0, d = 0.0;
    for (int i = threadIdx.x; i < n; i += 256) {
        float2 p = partials[i];
        f += (double)p.x;
        d += (double)p.y;
    }
    #pragma unroll
    for (int off = 32; off > 0; off >>= 1) {
        f += __shfl_down(f, off, 64);
        d += __shfl_down(d, off, 64);
    }
    __shared__ double sf[4], sd[4];
    const int wave = threadIdx.x >> 6, lane = threadIdx.x & 63;
    if (lane == 0) { sf[wave] = f; sd[wave] = d; }
    __syncthreads();
    if (threadIdx.x == 0) {
        double F = sf[0] + sf[1] + sf[2] + sf[3];
        double D = sd[0] + sd[1] + sd[2] + sd[3];
        double inv = 1.0 / ((double)Bb * (double)Nn);
        float focal = (float)(F * inv);
        float dist  = (float)(D * inv);
        out[0] = focal + dist;   // total (DISTANCE_WEIGHT = 1)
        out[1] = focal;
        out[2] = dist;
    }
}

extern "C" void kernel_launch(void* const* d_in, const int* in_sizes, int n_in,
                              void* d_out, int out_size, void* d_ws, size_t ws_size,
                              hipStream_t stream) {
    const float* inputs  = (const float*)d_in[0];
    const float* targets = (const float*)d_in[1];
    const float* pts     = (const float*)d_in[2];
    const float* corners = (const float*)d_in[3];
    float* out = (float*)d_out;
    float2* partials = (float2*)d_ws;

    dim3 grid(Nn / (BLOCK * PPT), Bb);   // (16, 64) = 1024 blocks
    acl_main<<<grid, BLOCK, 0, stream>>>(inputs, targets, pts, corners, partials);
    acl_final<<<1, 256, 0, stream>>>(partials, grid.x * grid.y, out);
}